// Round 1
// baseline (1058.628 us; speedup 1.0000x reference)
//
#include <hip/hip_runtime.h>

#define NT 2000
#define NS 2048
#define NH 16
#define UNROLL 8

// One thread per (site, head) chain. nh = fastest-varying 4 bits of the global
// thread id so that Fh/Hh/Gh stores (layout [t][s][nh]) are lane-coalesced.
// Q[t][s] = sum over nh of contrib -> 16-lane xor-butterfly; butterflies are
// batched UNROLL at a time so their DS latencies overlap (only ~1 wave/SIMD is
// resident -> no TLP to hide latency, must come from ILP).
__global__ __launch_bounds__(64) void waternet_kernel(
    const float* __restrict__ P, const float* __restrict__ T,
    const float* __restrict__ E,
    const float* __restrict__ w_o, const float* __restrict__ wF,
    const float* __restrict__ wG, const float* __restrict__ wl,
    const float* __restrict__ we, const float* __restrict__ wk,
    const float* __restrict__ ws,
    float* __restrict__ Q, float* __restrict__ Fh,
    float* __restrict__ Hh, float* __restrict__ Gh)
{
    const int c  = blockIdx.x * 64 + threadIdx.x;   // 0 .. NS*NH-1
    const int s  = c >> 4;
    const int nh = c & 15;

    // ---- per-head parameter transforms (once) ----
    // softmax over w_o (16 values)
    float mx = -INFINITY;
    #pragma unroll
    for (int i = 0; i < NH; ++i) mx = fmaxf(mx, w_o[i]);
    float ssum = 0.f;
    #pragma unroll
    for (int i = 0; i < NH; ++i) ssum += expf(w_o[i] - mx);
    const float a = expf(w_o[nh] - mx) / ssum;

    const float melt  = expf(wF[nh]) + 1.0f;
    const float cap   = expf(2.0f * wl[nh]);
    const float swe   = 1.0f / (1.0f + expf(-we[nh]));
    const float swk   = 1.0f / (1.0f + expf(-wk[nh]));
    const float sws   = 1.0f / (1.0f + expf(-ws[nh]));
    const float swG   = 1.0f / (1.0f + expf(-wG[nh]));
    const float omsws = 1.0f - sws;

    float f = 0.0f, h = 0.0f, g = 0.0f;

    int li = s;                                   // load index into P/T/E
    size_t obase = (size_t)s * NH + nh;           // store index into Fh/Hh/Gh
    const int qi = s;                             // Q column

    // prefetch first group
    float Pb[UNROLL], Tb[UNROLL], Eb[UNROLL];
    #pragma unroll
    for (int j = 0; j < UNROLL; ++j) {
        Pb[j] = P[li]; Tb[j] = T[li]; Eb[j] = E[li]; li += NS;
    }

    for (int t0 = 0; t0 < NT; t0 += UNROLL) {
        float Pc[UNROLL], Tc[UNROLL], Ec[UNROLL];
        #pragma unroll
        for (int j = 0; j < UNROLL; ++j) { Pc[j] = Pb[j]; Tc[j] = Tb[j]; Ec[j] = Eb[j]; }

        // issue next group's loads early (independent, overlap with compute)
        if (t0 + UNROLL < NT) {
            #pragma unroll
            for (int j = 0; j < UNROLL; ++j) {
                Pb[j] = P[li]; Tb[j] = T[li]; Eb[j] = E[li]; li += NS;
            }
        }

        float qsv[UNROLL];
        #pragma unroll
        for (int j = 0; j < UNROLL; ++j) {
            const float Tk = Tc[j], Pk = Pc[j], Ek = Ec[j];
            // SnowBucket
            const float sm = fmaxf(Tk, 0.0f) * melt;
            const float m  = fminf(sm, f);
            f = f - m + (Tk < 0.0f ? Pk : 0.0f);
            const float x  = (Tk > 0.0f ? Pk : 0.0f) + m;
            // SoilBucket
            const float hn = h + x;
            const float h1 = fmaxf(hn - cap, 0.0f);
            const float q1 = fmaxf(h1 - Ek * swe, 0.0f);
            const float h2 = hn - h1;
            const float q2 = h2 * swk;
            h = h2 - q2;
            const float q2a = q2 * sws;
            const float q2b = q2 * omsws;
            // LinearBucket
            const float q3 = (q2b + g) * swG;
            g = g - q3 + q2b;
            qsv[j] = (q1 + q2a + q3) * a;

            Fh[obase] = f;
            Hh[obase] = h;
            Gh[obase] = g;
            obase += (size_t)NS * NH;
        }

        // 8 independent 16-lane butterflies -> latencies overlap
        #pragma unroll
        for (int j = 0; j < UNROLL; ++j) {
            float v = qsv[j];
            v += __shfl_xor(v, 1);
            v += __shfl_xor(v, 2);
            v += __shfl_xor(v, 4);
            v += __shfl_xor(v, 8);
            qsv[j] = v;
        }
        if (nh == 0) {
            #pragma unroll
            for (int j = 0; j < UNROLL; ++j)
                Q[(size_t)(t0 + j) * NS + qi] = qsv[j];
        }
    }
}

extern "C" void kernel_launch(void* const* d_in, const int* in_sizes, int n_in,
                              void* d_out, int out_size, void* d_ws, size_t ws_size,
                              hipStream_t stream) {
    const float* P   = (const float*)d_in[0];
    const float* T   = (const float*)d_in[1];
    const float* E   = (const float*)d_in[2];
    const float* w_o = (const float*)d_in[3];
    const float* wF  = (const float*)d_in[4];
    const float* wG  = (const float*)d_in[5];
    const float* wl  = (const float*)d_in[6];
    const float* we  = (const float*)d_in[7];
    const float* wk  = (const float*)d_in[8];
    const float* ws  = (const float*)d_in[9];

    float* Q  = (float*)d_out;
    float* Fh = Q  + (size_t)NT * NS;
    float* Hh = Fh + (size_t)NT * NS * NH;
    float* Gh = Hh + (size_t)NT * NS * NH;

    const int threads = NS * NH;          // 32768 chains
    dim3 block(64);
    dim3 grid(threads / 64);              // 512 blocks -> ~2 waves/CU
    waternet_kernel<<<grid, block, 0, stream>>>(P, T, E, w_o, wF, wG, wl, we, wk, ws,
                                                Q, Fh, Hh, Gh);
}